// Round 3
// baseline (64.568 us; speedup 1.0000x reference)
//
#include <hip/hip_runtime.h>
#include <math.h>

#define NB 256
#define NC 3
#define NH 224
#define NW 224
#define HW (NH * NW)          // 50176
#define CHW (NC * HW)         // 150528
#define GP 8                  // pixels per thread
#define NT 128                // threads per block (2 waves)
#define WGR (NW / GP)         // 28 pixel-groups per row
#define GPI (HW / GP)         // 6272 groups per image
#define BPI (GPI / NT)        // 49 blocks per image

typedef float f32x4 __attribute__((ext_vector_type(4)));   // native vector: OK for nontemporal builtins

struct __align__(16) Params {
    float b255, c_fac, s_fac, cos_h, sh;   // b255 = b_fac/255, sh = sin_h*0.5
    int   flip, apply, top, left, he, we;
};

// Per-image scalar parameters. MUST be bit-exact vs the fp32 reference for the
// erase-box integers (he/we/top/left) -> no FMA contraction here.
__device__ inline void compute_params(int b,
    const float* __restrict__ flip_u, const float* __restrict__ bj_u,
    const float* __restrict__ cj_u,   const float* __restrict__ sj_u,
    const float* __restrict__ hue_u,  const float* __restrict__ erase_u,
    const float* __restrict__ area_u, const float* __restrict__ aspect_u,
    const float* __restrict__ top_u,  const float* __restrict__ left_u,
    Params* p)
{
#pragma clang fp contract(off)
    p->flip  = (flip_u[b] > 0.5f) ? 1 : 0;
    float b_fac = 1.0f + (bj_u[b] * 2.0f - 1.0f) * 0.4f;
    p->b255  = b_fac * (1.0f / 255.0f);
    p->c_fac = 1.0f + (cj_u[b] * 2.0f - 1.0f) * 0.4f;
    p->s_fac = 1.0f + (sj_u[b] * 2.0f - 1.0f) * 0.4f;
    float h_fac = (hue_u[b] * 2.0f - 1.0f) * 0.1f * 0.5f;
    float ang   = h_fac * 3.14159f;
    p->cos_h = cosf(ang);
    p->sh    = sinf(ang) * 0.5f;

    float ta     = (0.02f + area_u[b] * 0.31f) * (float)HW;
    float aspect = 0.3f + aspect_u[b] * 3.0f;
    int he = (int)rintf(sqrtf(ta * aspect));   // jnp.round = half-to-even = rintf
    int we = (int)rintf(sqrtf(ta / aspect));
    int apply = (erase_u[b] < 0.25f) && (he < NH) && (we < NW);
    int th = NH - he + 1; if (th < 1) th = 1;
    int tw = NW - we + 1; if (tw < 1) tw = 1;
    p->top  = (int)floorf(top_u[b]  * (float)th);
    p->left = (int)floorf(left_u[b] * (float)tw);
    p->he = he; p->we = we; p->apply = apply;
}

__global__ __launch_bounds__(NT) void aug_kernel(
    const int*   __restrict__ x,
    const float* __restrict__ flip_u, const float* __restrict__ bj_u,
    const float* __restrict__ cj_u,   const float* __restrict__ sj_u,
    const float* __restrict__ hue_u,  const float* __restrict__ erase_u,
    const float* __restrict__ area_u, const float* __restrict__ aspect_u,
    const float* __restrict__ top_u,  const float* __restrict__ left_u,
    const float* __restrict__ noise,  const float* __restrict__ mean,
    const float* __restrict__ stdv,
    float* __restrict__ out)
{
    __shared__ Params sp;
    __shared__ float smean[3], sinv[3];

    const int bimg = blockIdx.x / BPI;
    if (threadIdx.x == 0) {
        compute_params(bimg, flip_u, bj_u, cj_u, sj_u, hue_u, erase_u,
                       area_u, aspect_u, top_u, left_u, &sp);
        smean[0] = mean[0]; smean[1] = mean[1]; smean[2] = mean[2];
        sinv[0] = 1.0f / stdv[0]; sinv[1] = 1.0f / stdv[1]; sinv[2] = 1.0f / stdv[2];
    }
    __syncthreads();

    const int r  = (blockIdx.x % BPI) * NT + threadIdx.x;  // 8-pixel group within image
    const int h  = r / WGR;
    const int w8 = (r - h * WGR) * GP;

    const int base  = bimg * CHW + h * NW;                 // fits in int32
    const int srcw8 = sp.flip ? (NW - GP - w8) : w8;       // stays 16B-aligned

    // issue all 6 loads up front (max MLP)
    union { int4 v4[2]; int a[8]; } xi[3];
    xi[0].v4[0] = *(const int4*)(x + base          + srcw8);
    xi[0].v4[1] = *(const int4*)(x + base          + srcw8 + 4);
    xi[1].v4[0] = *(const int4*)(x + base + HW     + srcw8);
    xi[1].v4[1] = *(const int4*)(x + base + HW     + srcw8 + 4);
    xi[2].v4[0] = *(const int4*)(x + base + 2*HW   + srcw8);
    xi[2].v4[1] = *(const int4*)(x + base + 2*HW   + srcw8 + 4);

    const float b255 = sp.b255, cfac = sp.c_fac, sfac = sp.s_fac;
    const float ch = sp.cos_h, sh = sp.sh;
    const float m0 = smean[0], m1 = smean[1], m2 = smean[2];
    const float i0 = sinv[0], i1 = sinv[1], i2 = sinv[2];
    const float third = 1.0f / 3.0f;
    const int   flip = sp.flip;

    float v[3][GP];
    #pragma unroll
    for (int i = 0; i < GP; ++i) {
        const int src = flip ? (GP - 1 - i) : i;
        // brightness folded into the /255 conversion
        float r_ = (float)xi[0].a[src] * b255;
        float g_ = (float)xi[1].a[src] * b255;
        float b_ = (float)xi[2].a[src] * b255;

        float gray = (r_ + g_ + b_) * third;          // contrast
        r_ = gray + cfac * (r_ - gray);
        g_ = gray + cfac * (g_ - gray);
        b_ = gray + cfac * (b_ - gray);

        gray = (r_ + g_ + b_) * third;                // saturation
        r_ = gray + sfac * (r_ - gray);
        g_ = gray + sfac * (g_ - gray);
        b_ = gray + sfac * (b_ - gray);

        gray = (r_ + g_ + b_) * third;                // hue rotation
        float rn = gray + (r_ - gray) * ch + (g_ - b_) * sh;
        float gn = gray + (g_ - gray) * ch + (b_ - r_) * sh;
        float bn = gray + (b_ - gray) * ch + (r_ - g_) * sh;

        rn = fminf(fmaxf(rn, 0.0f), 1.0f);
        gn = fminf(fmaxf(gn, 0.0f), 1.0f);
        bn = fminf(fmaxf(bn, 0.0f), 1.0f);

        v[0][i] = (rn - m0) * i0;
        v[1][i] = (gn - m1) * i1;
        v[2][i] = (bn - m2) * i2;
    }

    // random erase: overwrite with noise inside the box
    const bool rowin = sp.apply && (h >= sp.top) && (h < sp.top + sp.he);
    if (rowin) {
        #pragma unroll
        for (int i = 0; i < GP; ++i) {
            const int col = w8 + i;
            if (col >= sp.left && col < sp.left + sp.we) {
                v[0][i] = noise[base          + col];
                v[1][i] = noise[base + HW     + col];
                v[2][i] = noise[base + 2*HW   + col];
            }
        }
    }

    // non-temporal streaming stores: don't let the 150MB output evict x from L2/LLC
    #pragma unroll
    for (int c = 0; c < 3; ++c) {
        f32x4 lo = { v[c][0], v[c][1], v[c][2], v[c][3] };
        f32x4 hi = { v[c][4], v[c][5], v[c][6], v[c][7] };
        __builtin_nontemporal_store(lo, (f32x4*)(out + base + c*HW + w8));
        __builtin_nontemporal_store(hi, (f32x4*)(out + base + c*HW + w8 + 4));
    }
}

extern "C" void kernel_launch(void* const* d_in, const int* in_sizes, int n_in,
                              void* d_out, int out_size, void* d_ws, size_t ws_size,
                              hipStream_t stream) {
    const int*   x        = (const int*)  d_in[0];
    const float* flip_u   = (const float*)d_in[1];
    const float* bj_u     = (const float*)d_in[2];
    const float* cj_u     = (const float*)d_in[3];
    const float* sj_u     = (const float*)d_in[4];
    const float* hue_u    = (const float*)d_in[5];
    const float* erase_u  = (const float*)d_in[6];
    const float* area_u   = (const float*)d_in[7];
    const float* aspect_u = (const float*)d_in[8];
    const float* top_u    = (const float*)d_in[9];
    const float* left_u   = (const float*)d_in[10];
    const float* noise    = (const float*)d_in[11];
    const float* mean     = (const float*)d_in[12];
    const float* stdv     = (const float*)d_in[13];
    float* out = (float*)d_out;

    const int grid = NB * BPI;   // 256 images * 49 blocks = 12544
    aug_kernel<<<grid, NT, 0, stream>>>(x, flip_u, bj_u, cj_u, sj_u, hue_u,
                                        erase_u, area_u, aspect_u, top_u, left_u,
                                        noise, mean, stdv, out);
}

// Round 4
// 60.855 us; speedup vs baseline: 1.0610x; 1.0610x over previous
//
#include <hip/hip_runtime.h>
#include <math.h>

#define NB 256
#define NC 3
#define NH 224
#define NW 224
#define HW (NH * NW)          // 50176
#define CHW (NC * HW)         // 150528
#define GP 4                  // pixels per thread
#define NT 256                // threads per block (4 waves)
#define WGR (NW / GP)         // 56 pixel-groups per row
#define GPI (HW / GP)         // 12544 groups per image
#define BPI (GPI / NT)        // 49 blocks per image

struct __align__(16) Params {
    float b255;               // b_fac / 255
    float k1;                 // c_fac * s_fac * cos_h
    float k2;                 // c_fac * s_fac * sin_h * 0.5
    int   flip, apply, top, left, he, we;
};

// Per-image scalar parameters. The erase-box integers (he/we/top/left) MUST be
// bit-exact vs the fp32 reference -> no FMA contraction in this function.
__device__ inline void compute_params(int b,
    const float* __restrict__ flip_u, const float* __restrict__ bj_u,
    const float* __restrict__ cj_u,   const float* __restrict__ sj_u,
    const float* __restrict__ hue_u,  const float* __restrict__ erase_u,
    const float* __restrict__ area_u, const float* __restrict__ aspect_u,
    const float* __restrict__ top_u,  const float* __restrict__ left_u,
    Params* p)
{
#pragma clang fp contract(off)
    p->flip  = (flip_u[b] > 0.5f) ? 1 : 0;
    float b_fac = 1.0f + (bj_u[b] * 2.0f - 1.0f) * 0.4f;
    float c_fac = 1.0f + (cj_u[b] * 2.0f - 1.0f) * 0.4f;
    float s_fac = 1.0f + (sj_u[b] * 2.0f - 1.0f) * 0.4f;
    float h_fac = (hue_u[b] * 2.0f - 1.0f) * 0.1f * 0.5f;
    float ang   = h_fac * 3.14159f;
    // contrast+saturation preserve the per-pixel mean, so the three gray
    // computations in the reference are identical -> the whole
    // contrast->saturation->hue chain is one affine map about one gray:
    //   out_c = gray + k1*(c - gray) + k2*cross_c
    float cs = c_fac * s_fac;
    p->b255 = b_fac * (1.0f / 255.0f);
    p->k1   = cs * cosf(ang);
    p->k2   = cs * sinf(ang) * 0.5f;

    float ta     = (0.02f + area_u[b] * 0.31f) * (float)HW;
    float aspect = 0.3f + aspect_u[b] * 3.0f;
    int he = (int)rintf(sqrtf(ta * aspect));   // jnp.round = half-to-even = rintf
    int we = (int)rintf(sqrtf(ta / aspect));
    int apply = (erase_u[b] < 0.25f) && (he < NH) && (we < NW);
    int th = NH - he + 1; if (th < 1) th = 1;
    int tw = NW - we + 1; if (tw < 1) tw = 1;
    p->top  = (int)floorf(top_u[b]  * (float)th);
    p->left = (int)floorf(left_u[b] * (float)tw);
    p->he = he; p->we = we; p->apply = apply;
}

__global__ __launch_bounds__(NT) void aug_kernel(
    const int*   __restrict__ x,
    const float* __restrict__ flip_u, const float* __restrict__ bj_u,
    const float* __restrict__ cj_u,   const float* __restrict__ sj_u,
    const float* __restrict__ hue_u,  const float* __restrict__ erase_u,
    const float* __restrict__ area_u, const float* __restrict__ aspect_u,
    const float* __restrict__ top_u,  const float* __restrict__ left_u,
    const float* __restrict__ noise,  const float* __restrict__ mean,
    const float* __restrict__ stdv,
    float* __restrict__ out)
{
    __shared__ Params sp;
    __shared__ float sinv[3], smi[3];   // 1/std, mean/std

    const int bimg = blockIdx.x / BPI;
    if (threadIdx.x == 0) {
        compute_params(bimg, flip_u, bj_u, cj_u, sj_u, hue_u, erase_u,
                       area_u, aspect_u, top_u, left_u, &sp);
        #pragma unroll
        for (int c = 0; c < 3; ++c) {
            float inv = 1.0f / stdv[c];
            sinv[c] = inv;
            smi[c]  = mean[c] * inv;
        }
    }
    __syncthreads();

    const int r  = (blockIdx.x % BPI) * NT + threadIdx.x;  // 4-pixel group within image
    const int h  = r / WGR;
    const int w4 = (r - h * WGR) * GP;

    const int base  = bimg * CHW + h * NW;                 // fits in int32
    const int srcw4 = sp.flip ? (NW - GP - w4) : w4;       // stays 16B-aligned

    int4 xi0 = *(const int4*)(x + base          + srcw4);
    int4 xi1 = *(const int4*)(x + base + HW     + srcw4);
    int4 xi2 = *(const int4*)(x + base + 2*HW   + srcw4);

    const float b255 = sp.b255, k1 = sp.k1, k2 = sp.k2;
    const float i0 = sinv[0], i1 = sinv[1], i2 = sinv[2];
    const float mi0 = smi[0], mi1 = smi[1], mi2 = smi[2];
    const float third = 1.0f / 3.0f;
    const int   flip = sp.flip;

    float v[3][GP];
    {
        const int* p0 = (const int*)&xi0;
        const int* p1 = (const int*)&xi1;
        const int* p2 = (const int*)&xi2;
        #pragma unroll
        for (int i = 0; i < GP; ++i) {
            const int src = flip ? (GP - 1 - i) : i;
            // brightness folded into /255 conversion
            float r_ = (float)p0[src] * b255;
            float g_ = (float)p1[src] * b255;
            float b_ = (float)p2[src] * b255;

            float gray = (r_ + g_ + b_) * third;
            // fused contrast+saturation+hue (single affine map about gray)
            float rn = fmaf(k2, g_ - b_, fmaf(k1, r_ - gray, gray));
            float gn = fmaf(k2, b_ - r_, fmaf(k1, g_ - gray, gray));
            float bn = fmaf(k2, r_ - g_, fmaf(k1, b_ - gray, gray));

            rn = fminf(fmaxf(rn, 0.0f), 1.0f);   // -> v_med3_f32
            gn = fminf(fmaxf(gn, 0.0f), 1.0f);
            bn = fminf(fmaxf(bn, 0.0f), 1.0f);

            // (x - m)/s = x*(1/s) - m*(1/s)
            v[0][i] = fmaf(rn, i0, -mi0);
            v[1][i] = fmaf(gn, i1, -mi1);
            v[2][i] = fmaf(bn, i2, -mi2);
        }
    }

    // random erase: overwrite with noise inside the box
    const bool rowin = sp.apply && (h >= sp.top) && (h < sp.top + sp.he);
    if (rowin) {
        #pragma unroll
        for (int i = 0; i < GP; ++i) {
            const int col = w4 + i;
            if (col >= sp.left && col < sp.left + sp.we) {
                v[0][i] = noise[base          + col];
                v[1][i] = noise[base + HW     + col];
                v[2][i] = noise[base + 2*HW   + col];
            }
        }
    }

    *(float4*)(out + base          + w4) = make_float4(v[0][0], v[0][1], v[0][2], v[0][3]);
    *(float4*)(out + base + HW     + w4) = make_float4(v[1][0], v[1][1], v[1][2], v[1][3]);
    *(float4*)(out + base + 2*HW   + w4) = make_float4(v[2][0], v[2][1], v[2][2], v[2][3]);
}

extern "C" void kernel_launch(void* const* d_in, const int* in_sizes, int n_in,
                              void* d_out, int out_size, void* d_ws, size_t ws_size,
                              hipStream_t stream) {
    const int*   x        = (const int*)  d_in[0];
    const float* flip_u   = (const float*)d_in[1];
    const float* bj_u     = (const float*)d_in[2];
    const float* cj_u     = (const float*)d_in[3];
    const float* sj_u     = (const float*)d_in[4];
    const float* hue_u    = (const float*)d_in[5];
    const float* erase_u  = (const float*)d_in[6];
    const float* area_u   = (const float*)d_in[7];
    const float* aspect_u = (const float*)d_in[8];
    const float* top_u    = (const float*)d_in[9];
    const float* left_u   = (const float*)d_in[10];
    const float* noise    = (const float*)d_in[11];
    const float* mean     = (const float*)d_in[12];
    const float* stdv     = (const float*)d_in[13];
    float* out = (float*)d_out;

    const int grid = NB * BPI;   // 256 images * 49 blocks = 12544
    aug_kernel<<<grid, NT, 0, stream>>>(x, flip_u, bj_u, cj_u, sj_u, hue_u,
                                        erase_u, area_u, aspect_u, top_u, left_u,
                                        noise, mean, stdv, out);
}